// Round 10
// baseline (719.413 us; speedup 1.0000x reference)
//
#include <hip/hip_runtime.h>
#include <hip/hip_bf16.h>
#include <stdint.h>

#define T_STEPS 64
#define BATCH   512
#define SDIM    10
#define HDIM    1024
#define GDIM    4096   // 4*H

typedef __attribute__((ext_vector_type(8))) short bf16x8;
typedef __attribute__((ext_vector_type(4))) float f32x4;

#define MFMA16(a,b,c) __builtin_amdgcn_mfma_f32_16x16x32_bf16(a,b,c,0,0,0)
#define VMW(N) asm volatile("s_waitcnt vmcnt(" #N ")" ::: "memory")
#define LGKM0  asm volatile("s_waitcnt lgkmcnt(0)" ::: "memory")
#define SBAR   do { __builtin_amdgcn_s_barrier(); __builtin_amdgcn_sched_barrier(0); } while (0)

__device__ __forceinline__ float sigmoidf_(float x) { return 1.0f / (1.0f + __expf(-x)); }
__device__ __forceinline__ float tanhf_(float x) {
    x = fminf(15.0f, fmaxf(-15.0f, x));
    float e = __expf(2.0f * x);
    return (e - 1.0f) / (e + 1.0f);
}
__device__ __forceinline__ short bf16bits(float v) {
    __hip_bfloat16 hb = __float2bfloat16(v);
    return *(short*)&hb;
}

// async global->LDS, 16B/lane; LDS dest = wave-uniform base + lane*16
__device__ __forceinline__ void gload16(const void* g, void* l) {
    __builtin_amdgcn_global_load_lds(
        (const __attribute__((address_space(1))) unsigned int*)g,
        (__attribute__((address_space(3))) unsigned int*)l, 16, 0, 0);
}

// ---------------------------------------------------------------------------
// Merged setup + weq (independent work, branch on blockIdx):
//  blocks 0..2047:  W_hh -> bf16; W_out -> bf16 transposed+padded [16][1024]
//  blocks 2048..2303: weq_bf[n][32] bf16: cols 0..9 = sum_k W_in[s][k]*W_ih[n][k];
//                     col 10 = b_ih+b_hh+b_in@W_ih^T; cols 11..31 = 0.
// ---------------------------------------------------------------------------
__launch_bounds__(256)
__global__ void setup_weq_kernel(const float* __restrict__ W_hh,
                                 const float* __restrict__ W_out,
                                 const float* __restrict__ W_in,
                                 const float* __restrict__ W_ih,
                                 const float* __restrict__ b_in,
                                 const float* __restrict__ b_ih,
                                 const float* __restrict__ b_hh,
                                 __hip_bfloat16* __restrict__ whh_bf,
                                 __hip_bfloat16* __restrict__ wot_bf,
                                 __hip_bfloat16* __restrict__ weq_bf) {
    __shared__ float sWin[SDIM * HDIM];  // 40 KB (used by weq blocks only)
    __shared__ float sbin[HDIM];
    const int tid = threadIdx.x;
    if (blockIdx.x < 2048) {
        int idx = blockIdx.x * 256 + tid;
        int stride = 2048 * 256;
        for (int i = idx; i < GDIM * HDIM; i += stride)
            whh_bf[i] = __float2bfloat16(W_hh[i]);
        for (int i = idx; i < 16 * HDIM; i += stride) {
            int n = i >> 10, k = i & 1023;
            wot_bf[i] = (n < SDIM) ? __float2bfloat16(W_out[k * SDIM + n]) : __float2bfloat16(0.0f);
        }
        return;
    }
    const int wblk = blockIdx.x - 2048;   // 0..255
    for (int i = tid; i < SDIM * HDIM; i += 256) sWin[i] = W_in[i];
    for (int i = tid; i < HDIM; i += 256) sbin[i] = b_in[i];
    __syncthreads();
    const int wv = tid >> 6, lane = tid & 63;
#pragma unroll
    for (int j = 0; j < 4; ++j) {
        int n = wblk * 16 + wv * 4 + j;
        float acc[SDIM + 1];
#pragma unroll
        for (int s = 0; s <= SDIM; s++) acc[s] = 0.0f;
        for (int it = 0; it < HDIM / 64; ++it) {
            int k = lane + it * 64;
            float wih = W_ih[n * HDIM + k];
#pragma unroll
            for (int s = 0; s < SDIM; s++) acc[s] += wih * sWin[s * HDIM + k];
            acc[SDIM] += wih * sbin[k];
        }
#pragma unroll
        for (int s = 0; s <= SDIM; s++) {
            float v = acc[s];
            for (int off = 32; off > 0; off >>= 1) v += __shfl_down(v, off);
            acc[s] = v;
        }
        if (lane == 0) {
            __hip_bfloat16 rowv[32];
#pragma unroll
            for (int s = 0; s < SDIM; s++) rowv[s] = __float2bfloat16(acc[s]);
            rowv[10] = __float2bfloat16(acc[SDIM] + b_ih[n] + b_hh[n]);
#pragma unroll
            for (int s = 11; s < 32; s++) rowv[s] = __float2bfloat16(0.0f);
#pragma unroll
            for (int q = 0; q < 4; q++)
                ((uint4*)(weq_bf + n * 32))[q] = ((uint4*)rowv)[q];
        }
    }
}

// ---------------------------------------------------------------------------
// t = 0: h_prev = 0, gates = input path only (bf16 weights, matches steps).
// ---------------------------------------------------------------------------
__launch_bounds__(256)
__global__ void t0_kernel(const float* __restrict__ inputs,
                          const __hip_bfloat16* __restrict__ weq_bf,
                          __hip_bfloat16* __restrict__ hs,
                          float* __restrict__ c_buf) {
    int gidx = blockIdx.x * 256 + threadIdx.x;
    int b = gidx >> 10, h = gidx & 1023;
    float xv[SDIM];
#pragma unroll
    for (int s = 0; s < SDIM; s++) xv[s] = inputs[b * SDIM + s];
    float pre[4];
#pragma unroll
    for (int g = 0; g < 4; ++g) {
        const __hip_bfloat16* wr = weq_bf + (size_t)(g * HDIM + h) * 32;
        float a = __bfloat162float(wr[10]);
#pragma unroll
        for (int s = 0; s < SDIM; s++) a += xv[s] * __bfloat162float(wr[s]);
        pre[g] = a;
    }
    float ig = sigmoidf_(pre[0]);
    float gg = tanhf_(pre[2]);
    float og = sigmoidf_(pre[3]);
    float cn = ig * gg;
    c_buf[gidx] = cn;
    hs[gidx] = __float2bfloat16(og * tanhf_(cn));
}

// ---------------------------------------------------------------------------
// One LSTM timestep. Block 64 batch-rows x 128 cols (32 h x 4 gates,
// gate-minor col = hh*4+g). 512 thr = 8 waves (2m x 4n), wave tile 32x32.
// K augmented: 1024 + 32 ([x|1|0]@[Weq|beq]). BK=128 intervals, depth-3
// 48KB LDS buffers; counted vmcnt(6) steady, vmcnt(0) only last interval.
// Single-barrier aug fill (chunk built in regs, one store); c_buf prefetched
// in prologue. 256B LDS rows, chunk ^= row&15 swizzle (involution both sides).
// Grid 256 = 8m x 32n, XCD-major n (W_hh stripe L2-resident per XCD).
// ---------------------------------------------------------------------------
__launch_bounds__(512, 1)
__global__ void step_kernel(const float* __restrict__ inputs,
                            const __hip_bfloat16* __restrict__ weq_bf,
                            const __hip_bfloat16* __restrict__ whh,
                            __hip_bfloat16* __restrict__ hs,
                            float* __restrict__ c_buf,
                            int t) {
    // 3 bufs x 49152 (A [64][256B] + B [128][256B]); X f32[64][128] aliases buf0;
    // augA [64][128B] + augB [128][128B] alias buf2 ([98304..122880)).
    __shared__ __align__(16) unsigned char lds[147456];
    unsigned char* augA = lds + 98304;
    unsigned char* augB = lds + 106496;

    const int tid = threadIdx.x;
    const int wv = tid >> 6, lane = tid & 63;
    const int wm = wv >> 2, wn = wv & 3;   // 2m x 4n
    const int lr = lane & 15, lk = lane >> 4;

    const int bid = blockIdx.x;
    const int nb = (bid & 7) * 4 + ((bid >> 3) & 3);  // XCD-major n-block
    const int mb = bid >> 5;
    const int m0 = mb * 64, h0 = nb * 32;

    const __hip_bfloat16* hprev = hs + (size_t)(t - 1) * BATCH * HDIM;

    // ---- staging sources (pre-swizzled chunk: phys = lch ^ (row&15)) ----
    const int lrow = lane >> 4;   // 0..3 row within one gload
    const int lch  = lane & 15;   // phys 16B chunk
    const __hip_bfloat16* aS[2]; int aD[2];
#pragma unroll
    for (int j = 0; j < 2; j++) {
        int idx = wv * 2 + j;           // 0..15
        int row = idx * 4 + lrow;       // 0..63
        int ch  = lch ^ (row & 15);
        aS[j] = hprev + (size_t)(m0 + row) * HDIM + ch * 8;
        aD[j] = idx * 1024;
    }
    const __hip_bfloat16* bS[4]; int bD[4];
#pragma unroll
    for (int j = 0; j < 4; j++) {
        int idx = wv * 4 + j;           // 0..31
        int c   = idx * 4 + lrow;       // 0..127 (gate-minor col)
        int n   = (c & 3) * HDIM + h0 + (c >> 2);
        int ch  = lch ^ (c & 15);
        bS[j] = whh + (size_t)n * HDIM + ch * 8;
        bD[j] = 16384 + idx * 1024;
    }

    auto STAGE = [&](int kt) {
        const int base = (kt % 3) * 49152;
        const int ko = kt * 128;
        gload16(aS[0] + ko, lds + base + aD[0]);
        gload16(aS[1] + ko, lds + base + aD[1]);
        gload16(bS[0] + ko, lds + base + bD[0]);
        gload16(bS[1] + ko, lds + base + bD[1]);
        gload16(bS[2] + ko, lds + base + bD[2]);
        gload16(bS[3] + ko, lds + base + bD[3]);
    };

    // ---- prologue: issue stage DMAs, then single-pass aug fill ----
    STAGE(0); STAGE(1);   // 12 DMAs/wave in flight

    // c_buf prefetch (consumed in epilogue; no in-kernel dependency)
    const int erow = tid >> 3, ehq = tid & 7;
    const size_t egbase = (size_t)(m0 + erow) * HDIM + h0 + ehq * 4;
    float4 cold = *(const float4*)(c_buf + egbase);

    // augA: rows 0..63, logical 64B (32 cols): [x(10) | 1.0 | zeros].
    // Each of threads 0..255 builds one 16B chunk in regs -> one store.
    if (tid < 256) {
        int row = tid >> 2, ch = tid & 3;
        const float* xr = inputs + (size_t)(t * BATCH + m0 + row) * SDIM;
        short v[8] = {0, 0, 0, 0, 0, 0, 0, 0};
        if (ch == 0) {
#pragma unroll
            for (int q = 0; q < 8; q++) v[q] = bf16bits(xr[q]);
        } else if (ch == 1) {
            v[0] = bf16bits(xr[8]);
            v[1] = bf16bits(xr[9]);
            v[2] = (short)0x3F80;   // 1.0 bf16 at col 10
        }
        *(uint4*)(augA + ((row * 128 + ch * 16) ^ ((row & 7) << 4))) = *(uint4*)v;
    }
    // augB: weq rows (4 chunks per 128B row), single pass
    {
        const int wc = tid >> 2, wch = tid & 3;
        const int wn_idx = (wc & 3) * HDIM + h0 + (wc >> 2);
        uint4 wb = *(const uint4*)(weq_bf + (size_t)wn_idx * 32 + wch * 8);
        *(uint4*)(augB + wc * 128 + ((wch * 16) ^ ((wc & 7) << 4))) = wb;
    }
    LGKM0; SBAR;   // aug visible to all waves (single barrier round)

    // ---- fragment read offsets (main: 256B rows, swz = lr<<4) ----
    int aro[2], bro[2];
#pragma unroll
    for (int fm = 0; fm < 2; fm++) aro[fm] = (wm * 32 + fm * 16 + lr) * 256;
#pragma unroll
    for (int fn = 0; fn < 2; fn++) bro[fn] = (wn * 32 + fn * 16 + lr) * 256 + 16384;
    const int swz = lr << 4;

    // ---- aug k-step (input path + bias via MFMA; 128B rows, swz row&7) ----
    f32x4 acc[2][2];
#pragma unroll
    for (int fm = 0; fm < 2; fm++)
#pragma unroll
        for (int fn = 0; fn < 2; fn++) {
            f32x4 z = {0.f, 0.f, 0.f, 0.f};
            acc[fm][fn] = z;
        }
    {
        bf16x8 a[2], b[2];
#pragma unroll
        for (int fm = 0; fm < 2; fm++) {
            int row = wm * 32 + fm * 16 + lr;
            a[fm] = *(const bf16x8*)(augA + row * 128 + ((lk * 16) ^ ((row & 7) << 4)));
        }
#pragma unroll
        for (int fn = 0; fn < 2; fn++) {
            int c = wn * 32 + fn * 16 + lr;
            b[fn] = *(const bf16x8*)(augB + c * 128 + ((lk * 16) ^ ((c & 7) << 4)));
        }
#pragma unroll
        for (int fm = 0; fm < 2; fm++)
#pragma unroll
            for (int fn = 0; fn < 2; fn++)
                acc[fm][fn] = MFMA16(a[fm], b[fn], acc[fm][fn]);
    }
    LGKM0;  // retire aug ds_reads before any wave can pass i=0 barrier
            // and issue STAGE(2), which overwrites the aug region (buf2 alias)

    // ---- main K-loop: 8 intervals of 128, counted-vmcnt depth-3 pipeline ----
#pragma unroll
    for (int i = 0; i < 8; ++i) {
        if (i < 7) { VMW(6); } else { VMW(0); }
        SBAR;
        if (i < 6) STAGE(i + 2);
        const unsigned char* Ab = lds + (i % 3) * 49152;
        const unsigned char* Bb = Ab;  // bro includes +16384
#pragma unroll
        for (int ks = 0; ks < 4; ++ks) {
            const int lo = ks * 64 + lk * 16;
            bf16x8 a[2], b[2];
#pragma unroll
            for (int fm = 0; fm < 2; fm++)
                a[fm] = *(const bf16x8*)(Ab + aro[fm] + (lo ^ swz));
#pragma unroll
            for (int fn = 0; fn < 2; fn++)
                b[fn] = *(const bf16x8*)(Bb + bro[fn] + (lo ^ swz));
#pragma unroll
            for (int fm = 0; fm < 2; fm++)
#pragma unroll
                for (int fn = 0; fn < 2; fn++)
                    acc[fm][fn] = MFMA16(a[fm], b[fn], acc[fm][fn]);
        }
    }

    // ---- epilogue: X exchange (XOR-swizzled f32 [64][128] in buf0) ----
#pragma unroll
    for (int fm = 0; fm < 2; fm++)
#pragma unroll
        for (int fn = 0; fn < 2; fn++)
#pragma unroll
            for (int r = 0; r < 4; r++) {
                int row = wm * 32 + fm * 16 + lk * 4 + r;
                int col = wn * 32 + fn * 16 + lr;
                *(float*)(lds + ((row * 512 + col * 4) ^ ((row & 7) << 4))) = acc[fm][fn][r];
            }
    LGKM0; SBAR;

    {
        float cget[4] = {cold.x, cold.y, cold.z, cold.w};
        float cnew[4];
        short hv[4];
#pragma unroll
        for (int q = 0; q < 4; q++) {
            int hh = ehq * 4 + q;
            float4 g4 = *(const float4*)(lds + ((erow * 512 + hh * 16) ^ ((erow & 7) << 4)));
            float ig = sigmoidf_(g4.x);
            float fg = sigmoidf_(g4.y);
            float gg = tanhf_(g4.z);
            float og = sigmoidf_(g4.w);
            float cn = fg * cget[q] + ig * gg;
            cnew[q] = cn;
            hv[q] = bf16bits(og * tanhf_(cn));
        }
        *(float4*)(c_buf + egbase) = (float4){cnew[0], cnew[1], cnew[2], cnew[3]};
        *(uint2*)(hs + (size_t)t * BATCH * HDIM + egbase) = *(uint2*)hv;
    }
}

// ---------------------------------------------------------------------------
// out[b,t,s] = hs[t,b,:] @ W_out + b_out via MFMA (N padded 10->16).
// ---------------------------------------------------------------------------
__launch_bounds__(256)
__global__ void out_mfma(const __hip_bfloat16* __restrict__ hs,
                         const __hip_bfloat16* __restrict__ wot, // [16][1024]
                         const float* __restrict__ b_out,
                         float* __restrict__ out) {
    __shared__ __align__(16) unsigned char sW[32768];
    const int tid = threadIdx.x, lane = tid & 63, wv = tid >> 6;
    const int lr = lane & 15, lk = lane >> 4;
#pragma unroll
    for (int i = 0; i < 8; i++) {
        int q = tid + i * 256;
        int row = q >> 7, col = q & 127;
        uint4 v = *(const uint4*)(wot + row * 1024 + col * 8);
        *(uint4*)(sW + row * 2048 + ((col * 16) ^ ((row & 7) << 4))) = v;
    }
    float bo = (lr < SDIM) ? b_out[lr] : 0.0f;
    __syncthreads();
    const int sw = (lr & 7) << 4;
    const int brow = lr * 2048;
#pragma unroll
    for (int s2 = 0; s2 < 2; s2++) {
        int strip = blockIdx.x * 8 + wv * 2 + s2;
        const __hip_bfloat16* Ab = hs + (size_t)(strip * 16 + lr) * 1024 + lk * 8;
        f32x4 acc = {0.f, 0.f, 0.f, 0.f};
        for (int kc = 0; kc < 32; kc++) {
            bf16x8 a = *(const bf16x8*)(Ab + kc * 32);
            bf16x8 b = *(const bf16x8*)(sW + brow + ((kc * 64 + lk * 16) ^ sw));
            acc = MFMA16(a, b, acc);
        }
        if (lr < SDIM) {
#pragma unroll
            for (int r = 0; r < 4; r++) {
                int grow = strip * 16 + lk * 4 + r;
                out[(grow & 511) * (T_STEPS * SDIM) + (grow >> 9) * SDIM + lr] = acc[r] + bo;
            }
        }
    }
}

// ---------------------------------------------------------------------------
extern "C" void kernel_launch(void* const* d_in, const int* in_sizes, int n_in,
                              void* d_out, int out_size, void* d_ws, size_t ws_size,
                              hipStream_t stream) {
    const float* inputs = (const float*)d_in[0];
    const float* W_in   = (const float*)d_in[1];
    const float* b_in   = (const float*)d_in[2];
    const float* W_ih   = (const float*)d_in[3];
    const float* W_hh   = (const float*)d_in[4];
    const float* b_ih   = (const float*)d_in[5];
    const float* b_hh   = (const float*)d_in[6];
    const float* W_out  = (const float*)d_in[7];
    const float* b_out  = (const float*)d_in[8];
    float* out = (float*)d_out;

    uint8_t* ws = (uint8_t*)d_ws;
    __hip_bfloat16* whh_bf = (__hip_bfloat16*)(ws);                    //  8 MB
    __hip_bfloat16* hs     = (__hip_bfloat16*)(ws + 8388608ull);       // 64 MB
    float*          c_buf  = (float*)(ws + 75497472ull);               //  2 MB
    __hip_bfloat16* wot_bf = (__hip_bfloat16*)(ws + 77594624ull);      // 32 KB
    __hip_bfloat16* weq_bf = (__hip_bfloat16*)(ws + 77660160ull);      // 256 KB

    setup_weq_kernel<<<2304, 256, 0, stream>>>(W_hh, W_out, W_in, W_ih, b_in,
                                               b_ih, b_hh, whh_bf, wot_bf, weq_bf);
    t0_kernel<<<2048, 256, 0, stream>>>(inputs, weq_bf, hs, c_buf);
    for (int t = 1; t < T_STEPS; t++)
        step_kernel<<<256, 512, 0, stream>>>(inputs, weq_bf, whh_bf, hs, c_buf, t);
    out_mfma<<<256, 256, 0, stream>>>(hs, wot_bf, b_out, out);
}